// Round 1
// baseline (94.410 us; speedup 1.0000x reference)
//
#include <hip/hip_runtime.h>
#include <cstdint>

// B=4, N=256, D=128, HID=128, IN_DIM=516.
// G[i,j,h] = [|hi-hj| ; hi*hj] @ W1[256:512]  (K=256 fp8 MFMA, W x256) -- symmetric in (i,j)
// pre' = 256*pre = acc + PiB'[i,h] + Pjf'[j,h] + scal'(i,j)·w   (PiB',Pjf',scal' pre-scaled x256)
// L = relu(pre') @ (W2/256) + b2   (relu positively homogeneous -> no per-element descale)
// out[i,j] = out[j,i] = 0.5*(L_f + L_m) ; diag -1e9.
// R8 = R6 grid (2112 blocks, 64 pairs) + R7's register-B + swizzled sF (+ks-rotation),
//      no sNode (global L1), LDS 25.9KB -> 5 blocks/CU, LB(256,5).

typedef float f32x4 __attribute__((ext_vector_type(4)));

#define INV256 0.00390625f

__device__ __forceinline__ uint32_t pk4(float a, float b, float c, float d) {
  uint32_t u = __builtin_amdgcn_cvt_pk_fp8_f32(a, b, 0, false);
  u = __builtin_amdgcn_cvt_pk_fp8_f32(c, d, u, true);
  return u;
}
__device__ __forceinline__ uint32_t pkbf2(float lo, float hi) {
  uint32_t l = __builtin_bit_cast(uint32_t, lo);
  uint32_t h = __builtin_bit_cast(uint32_t, hi);
  return (l >> 16) | (h & 0xffff0000u);
}
__device__ __forceinline__ float ulo(uint32_t u) {
  return __builtin_bit_cast(float, u << 16);
}
__device__ __forceinline__ float uhi(uint32_t u) {
  return __builtin_bit_cast(float, u & 0xffff0000u);
}
__device__ __forceinline__ long mk64(uint32_t lo, uint32_t hi) {
  return (long)((((unsigned long long)hi) << 32) | lo);
}

// bid<32: pack fp8 B-image (lane-linear MFMA fragment order, values W1*256)
// bid in [32,1056): PiB' = 256*(node@W1[0:128] + b1) ; Pjf' = 256*(node@W1[128:256])
__global__ __launch_bounds__(128) void pre_k(const float* __restrict__ node,
                                             const float* __restrict__ W1,
                                             const float* __restrict__ b1,
                                             float* __restrict__ PiB,
                                             float* __restrict__ Pjf,
                                             uint32_t* __restrict__ W1f8) {
  int bid = blockIdx.x;
  int tid = threadIdx.x;
  if (bid < 32) {
    int ks = bid >> 2, nip = (bid >> 1) & 1, wn = bid & 1;
    int lane = tid & 63, nilow = tid >> 6;
    int quad = lane >> 4, col = lane & 15;
    int h = wn * 64 + (nip * 2 + nilow) * 16 + col;
    int k0 = ks * 32 + quad * 8;
    float w[8];
#pragma unroll
    for (int t = 0; t < 8; ++t) w[t] = W1[(256 + k0 + t) * 128 + h] * 256.0f;
    uint2 u;
    u.x = pk4(w[0], w[1], w[2], w[3]);
    u.y = pk4(w[4], w[5], w[6], w[7]);
    reinterpret_cast<uint2*>(W1f8)[(bid * 64 + lane) * 2 + nilow] = u;
  } else {
    __shared__ float sN[128];
    int row = bid - 32;  // 0..1023
    int h = tid;
    sN[h] = node[row * 128 + h];
    __syncthreads();
    float ai = 0.f, aj = 0.f;
#pragma unroll 8
    for (int d = 0; d < 128; ++d) {
      float v = sN[d];
      ai = fmaf(v, W1[d * 128 + h], ai);
      aj = fmaf(v, W1[(128 + d) * 128 + h], aj);
    }
    PiB[row * 128 + h] = 256.0f * (ai + b1[h]);
    Pjf[row * 128 + h] = 256.0f * aj;
  }
}

// grid 2112 = b(4) * 528 unordered 8-group pairs (I<=J). 64 pairs/block, K=256 fp8.
// waves: wn2 = tid>>6 owns h-cols [wn2*32, wn2*32+32) (ni tiles 2wn2, 2wn2+1).
__global__ __launch_bounds__(256, 5) void main_k(
    const float* __restrict__ node, const float* __restrict__ baseL,
    const float* __restrict__ compL, const float* __restrict__ W1,
    const float* __restrict__ W2, const float* __restrict__ b2,
    const uint32_t* __restrict__ W1f8, const float* __restrict__ PiB,
    const float* __restrict__ Pjf, float* __restrict__ out) {
  // sF: [ks 0..7][mi 0..3][q 0..3][scol 0..15] 8B, scol=(col+2q+4(ks&3))&15 -> 16384 B
  //   (overlaid post-MFMA by sP: [64 pairs][40] fp32 partials, fwd@0..15, mir@20..35)
  // sPP: [16 rows][132] u32 {bf16 PiB' | bf16 Pjf'} (rows 0-7 I-group, 8-15 J-group)
  // sScal: [64 pairs] uint4 bf16x2 {bl',sig'}{cl',sig'} fwd then mirror
  __shared__ __align__(16) char smem[16384 + 8448 + 1024];
  char* sF = smem;
  uint32_t* sPP = reinterpret_cast<uint32_t*>(smem + 16384);
  uint4* sScal = reinterpret_cast<uint4*>(smem + 16384 + 8448);
  float* sP = reinterpret_cast<float*>(smem);  // overlay

  const int tid = threadIdx.x;
  const int bx = blockIdx.x;
  const int b = bx / 528;
  const int t = bx - b * 528;
  int tI = (int)((65.0f - sqrtf(4225.0f - 8.0f * (float)t)) * 0.5f);
  tI = (tI < 0) ? 0 : (tI > 31 ? 31 : tI);
  while (((65 * tI - tI * tI) >> 1) > t) --tI;
  while (tI < 31 && ((65 * (tI + 1) - (tI + 1) * (tI + 1)) >> 1) <= t) ++tI;
  const int tJ = tI + (t - ((65 * tI - tI * tI) >> 1));
  const int I0 = tI * 8, J0 = tJ * 8;
  const int rowB = b * 256;

  const int lane = tid & 63;
  const int wn2 = tid >> 6;
  const int col = lane & 15, quad = lane >> 4;

  // ---- B-fragments to registers (32 VGPR), L2-broadcast, held all kernel ----
  const int uB = ((wn2 & 1) << 1) | (wn2 >> 1);
  uint4 gB[8];
#pragma unroll
  for (int ks = 0; ks < 8; ++ks)
    gB[ks] = reinterpret_cast<const uint4*>(W1f8)[(ks * 4 + uB) * 64 + lane];

  // ---- stage sPP: 16 rows x 128 u32 {PiB'|Pjf'} bf16-packed, coalesced ----
#pragma unroll
  for (int it = 0; it < 2; ++it) {
    int fidx = it * 256 + tid;  // 512 float4 slots
    int row = fidx >> 5, d4 = fidx & 31;
    int gr = rowB + ((row < 8) ? (I0 + row) : (J0 + row - 8));
    float4 a = reinterpret_cast<const float4*>(PiB + (size_t)gr * 128)[d4];
    float4 c = reinterpret_cast<const float4*>(Pjf + (size_t)gr * 128)[d4];
    uint4 u;
    u.x = pkbf2(a.x, c.x);
    u.y = pkbf2(a.y, c.y);
    u.z = pkbf2(a.z, c.z);
    u.w = pkbf2(a.w, c.w);
    *reinterpret_cast<uint4*>(&sPP[row * 132 + d4 * 4]) = u;
  }

  // ---- stage scal (x256), fwd (tid<64) and mirror (tid in [64,128)) ----
  if (tid < 128) {
    int p = tid & 63, dir = tid >> 6;
    int iN = I0 + (p >> 3), jN = J0 + (p & 7);
    int rr = dir ? jN : iN, cc = dir ? iN : jN;
    float bl = fminf(fmaxf(baseL[(size_t)(rowB + rr) * 256 + cc], -20.f), 20.f);
    float cl = fminf(fmaxf(compL[(size_t)(rowB + rr) * 256 + cc], -20.f), 20.f);
    uint2 u;
    u.x = pkbf2(256.f * bl, 256.f / (1.f + __expf(-bl)));
    u.y = pkbf2(256.f * cl, 256.f / (1.f + __expf(-cl)));
    *reinterpret_cast<uint2*>(reinterpret_cast<char*>(&sScal[p]) + dir * 8) = u;
  }

  // ---- per-lane epilogue constants (2 ni columns) ----
  float cB0[2], cB1[2], cB2[2], cB3[2], cW2[2];
#pragma unroll
  for (int ni = 0; ni < 2; ++ni) {
    int h = (wn2 * 2 + ni) * 16 + col;
    cB0[ni] = W1[512 * 128 + h];
    cB1[ni] = W1[513 * 128 + h];
    cB2[ni] = W1[514 * 128 + h];
    cB3[ni] = W1[515 * 128 + h];
    cW2[ni] = W2[h] * INV256;
  }
  const float b2v = b2[0];

  // ---- F-build: 64 pairs x 256 k fp8, node read direct from global (L1-hot) ----
  {
    const int d4 = tid & 31;  // float4 index in 128 dims
    const int rr = tid >> 5;  // j-row 0..7
    const int ks1 = d4 >> 3, qd = (d4 >> 1) & 3, kb = (d4 & 1) * 4;
    const int scolbase = 2 * qd + 4 * ks1;  // ks-rotation -> 2-way (free) write conflicts
    const float4 hj = *reinterpret_cast<const float4*>(node + (size_t)(rowB + J0 + rr) * 128 + d4 * 4);
#pragma unroll
    for (int ii = 0; ii < 8; ++ii) {
      const float4 hi = *reinterpret_cast<const float4*>(node + (size_t)(rowB + I0 + ii) * 128 + d4 * 4);
      uint32_t du = pk4(fabsf(hi.x - hj.x), fabsf(hi.y - hj.y),
                        fabsf(hi.z - hj.z), fabsf(hi.w - hj.w));
      uint32_t pu = pk4(hi.x * hj.x, hi.y * hj.y, hi.z * hj.z, hi.w * hj.w);
      int p = ii * 8 + rr;
      int colp = p & 15, mi = p >> 4;
      int scol = (colp + scolbase) & 15;
      uint32_t addr = mi * 512 + qd * 128 + scol * 8 + kb;
      *reinterpret_cast<uint32_t*>(sF + ks1 * 2048 + addr) = du;
      *reinterpret_cast<uint32_t*>(sF + (ks1 + 4) * 2048 + addr) = pu;
    }
  }
  __syncthreads();

  // ---- MFMA: acc[4 mi][2 ni], K=256; A from swizzled LDS, B from registers ----
  f32x4 acc[4][2] = {};
#pragma unroll
  for (int ks = 0; ks < 8; ++ks) {
    long bb0 = mk64(gB[ks].x, gB[ks].y);
    long bb1 = mk64(gB[ks].z, gB[ks].w);
    const int ascol = (col + 2 * quad + 4 * (ks & 3)) & 15;
    const char* aks = sF + ks * 2048 + quad * 128 + ascol * 8;
#pragma unroll
    for (int mi = 0; mi < 4; ++mi) {
      uint2 av = *reinterpret_cast<const uint2*>(aks + mi * 512);
      long aa = mk64(av.x, av.y);
      acc[mi][0] = __builtin_amdgcn_mfma_f32_16x16x32_fp8_fp8(aa, bb0, acc[mi][0], 0, 0, 0);
      acc[mi][1] = __builtin_amdgcn_mfma_f32_16x16x32_fp8_fp8(aa, bb1, acc[mi][1], 0, 0, 0);
    }
  }
  __syncthreads();  // sF reads done -> sP overlay writable

  // ---- epilogue: fwd+mirror, partial shfl reduce (xor 1,2), 4 partials/wave ----
  uint32_t uJ[4][2];
#pragma unroll
  for (int r = 0; r < 4; ++r)
#pragma unroll
    for (int ni = 0; ni < 2; ++ni)
      uJ[r][ni] = sPP[(8 + (quad & 1) * 4 + r) * 132 + (wn2 * 2 + ni) * 16 + col];

#pragma unroll
  for (int mi = 0; mi < 4; ++mi) {
    const int ii = mi * 2 + (quad >> 1);
    uint32_t uI[2];
#pragma unroll
    for (int ni = 0; ni < 2; ++ni)
      uI[ni] = sPP[ii * 132 + (wn2 * 2 + ni) * 16 + col];
#pragma unroll
    for (int r = 0; r < 4; ++r) {
      int p = mi * 16 + quad * 4 + r;  // C/D: pair row = quad*4 + r
      uint4 sc = sScal[p];
      float f0 = ulo(sc.x), f1 = uhi(sc.x), f2 = ulo(sc.y), f3 = uhi(sc.y);
      float m0 = ulo(sc.z), m1 = uhi(sc.z), m2 = ulo(sc.w), m3 = uhi(sc.w);
      float vf = 0.f, vm = 0.f;
#pragma unroll
      for (int ni = 0; ni < 2; ++ni) {
        float piI = ulo(uI[ni]), pjI = uhi(uI[ni]);
        float piJ = ulo(uJ[r][ni]), pjJ = uhi(uJ[r][ni]);
        float a = acc[mi][ni][r];
        float pf = (a + piI) + pjJ;
        pf = fmaf(f0, cB0[ni], pf);
        pf = fmaf(f1, cB1[ni], pf);
        pf = fmaf(f2, cB2[ni], pf);
        pf = fmaf(f3, cB3[ni], pf);
        float pm = (a + piJ) + pjI;
        pm = fmaf(m0, cB0[ni], pm);
        pm = fmaf(m1, cB1[ni], pm);
        pm = fmaf(m2, cB2[ni], pm);
        pm = fmaf(m3, cB3[ni], pm);
        vf = fmaf(fmaxf(pf, 0.f), cW2[ni], vf);
        vm = fmaf(fmaxf(pm, 0.f), cW2[ni], vm);
      }
      vf += __shfl_xor(vf, 1);
      vf += __shfl_xor(vf, 2);
      vm += __shfl_xor(vm, 1);
      vm += __shfl_xor(vm, 2);
      if ((col & 3) == 0) {
        int part = wn2 * 4 + (col >> 2);
        sP[p * 40 + part] = vf;
        sP[p * 40 + 20 + part] = vm;
      }
    }
  }
  __syncthreads();

  // ---- final: sum 16 fwd + 16 mirror partials, symmetric store ----
  if (tid < 64) {
    int p = tid;
    const float4* pf4 = reinterpret_cast<const float4*>(sP + p * 40);
    const float4* pm4 = reinterpret_cast<const float4*>(sP + p * 40 + 20);
    float4 fa = pf4[0], fb = pf4[1], fc = pf4[2], fd = pf4[3];
    float4 ma = pm4[0], mb = pm4[1], mc = pm4[2], md = pm4[3];
    float sumF = (fa.x + fa.y + fa.z + fa.w) + (fb.x + fb.y + fb.z + fb.w) +
                 (fc.x + fc.y + fc.z + fc.w) + (fd.x + fd.y + fd.z + fd.w);
    float sumM = (ma.x + ma.y + ma.z + ma.w) + (mb.x + mb.y + mb.z + mb.w) +
                 (mc.x + mc.y + mc.z + mc.w) + (md.x + md.y + md.z + md.w);
    float val = 0.5f * (sumF + sumM) + b2v;
    int iN = I0 + (p >> 3), jN = J0 + (p & 7);
    if (iN == jN) val = -1e9f;
    out[(size_t)(rowB + iN) * 256 + jN] = val;
    out[(size_t)(rowB + jN) * 256 + iN] = val;
  }
}

extern "C" void kernel_launch(void* const* d_in, const int* in_sizes, int n_in,
                              void* d_out, int out_size, void* d_ws, size_t ws_size,
                              hipStream_t stream) {
  const float* node = (const float*)d_in[0];   // [4,256,128]
  const float* baseL = (const float*)d_in[1];  // [4,256,256]
  const float* compL = (const float*)d_in[2];  // [4,256,256]
  const float* W1 = (const float*)d_in[3];     // [516,128]
  const float* b1 = (const float*)d_in[4];     // [128]
  const float* W2 = (const float*)d_in[5];     // [128,1]
  const float* b2 = (const float*)d_in[6];     // [1]
  float* out = (float*)d_out;                  // [4,256,256] fp32

  char* ws = (char*)d_ws;
  float* PiB = (float*)(ws);                        // 512 KB
  float* Pjf = (float*)(ws + (512 << 10));          // 512 KB
  uint32_t* W1f8 = (uint32_t*)(ws + (1024 << 10));  // 32 KB

  pre_k<<<1056, 128, 0, stream>>>(node, W1, b1, PiB, Pjf, W1f8);
  main_k<<<2112, 256, 0, stream>>>(node, baseL, compL, W1, W2, b2, W1f8, PiB, Pjf, out);
}

// Round 2
// 92.915 us; speedup vs baseline: 1.0161x; 1.0161x over previous
//
#include <hip/hip_runtime.h>
#include <cstdint>

// B=4, N=256, D=128, HID=128, IN_DIM=516.
// G[i,j,h] = [|hi-hj| ; hi*hj] @ W1[256:512]  (K=256 fp8 MFMA, W x256) -- symmetric in (i,j)
// pre' = 256*pre = acc + PiB'[i,h] + Pjf'[j,h] + S(i,j,h)   (PiB',Pjf',scal' pre-scaled x256)
// S = scal'(p) @ W1[512:516]  -- R9: moved onto the matrix pipe as a K=4 (padded to 32)
//     bf16 MFMA per (mi,ni,dir); was 256 scalar FMA + 128 unpacks per wave.
// L = relu(pre') @ (W2/256) + b2   (relu positively homogeneous -> no per-element descale)
// out[i,j] = out[j,i] = 0.5*(L_f + L_m) ; diag -1e9.
// R9 = R8 (2112 blocks, 64 pairs, register-B, swizzled sF, LB(256,5)) + scal-term MFMA.

typedef float f32x4 __attribute__((ext_vector_type(4)));
typedef short bf16x8 __attribute__((ext_vector_type(8)));

#define INV256 0.00390625f

__device__ __forceinline__ uint32_t pk4(float a, float b, float c, float d) {
  uint32_t u = __builtin_amdgcn_cvt_pk_fp8_f32(a, b, 0, false);
  u = __builtin_amdgcn_cvt_pk_fp8_f32(c, d, u, true);
  return u;
}
__device__ __forceinline__ uint32_t pkbf2(float lo, float hi) {
  uint32_t l = __builtin_bit_cast(uint32_t, lo);
  uint32_t h = __builtin_bit_cast(uint32_t, hi);
  return (l >> 16) | (h & 0xffff0000u);
}
// round-to-nearest-even bf16 pack (for W1[512:516] rows -> MFMA B operand)
__device__ __forceinline__ uint32_t rnebf(float x) {
  uint32_t u = __builtin_bit_cast(uint32_t, x);
  return (u + 0x7fffu + ((u >> 16) & 1u)) >> 16;
}
__device__ __forceinline__ uint32_t pkbf2r(float lo, float hi) {
  return rnebf(lo) | (rnebf(hi) << 16);
}
__device__ __forceinline__ float ulo(uint32_t u) {
  return __builtin_bit_cast(float, u << 16);
}
__device__ __forceinline__ float uhi(uint32_t u) {
  return __builtin_bit_cast(float, u & 0xffff0000u);
}
__device__ __forceinline__ long mk64(uint32_t lo, uint32_t hi) {
  return (long)((((unsigned long long)hi) << 32) | lo);
}
__device__ __forceinline__ bf16x8 mkbf8(uint32_t a, uint32_t b, uint32_t c, uint32_t d) {
  uint4 u;
  u.x = a; u.y = b; u.z = c; u.w = d;
  return __builtin_bit_cast(bf16x8, u);
}

// bid<32: pack fp8 B-image (lane-linear MFMA fragment order, values W1*256)
// bid in [32,1056): PiB' = 256*(node@W1[0:128] + b1) ; Pjf' = 256*(node@W1[128:256])
__global__ __launch_bounds__(128) void pre_k(const float* __restrict__ node,
                                             const float* __restrict__ W1,
                                             const float* __restrict__ b1,
                                             float* __restrict__ PiB,
                                             float* __restrict__ Pjf,
                                             uint32_t* __restrict__ W1f8) {
  int bid = blockIdx.x;
  int tid = threadIdx.x;
  if (bid < 32) {
    int ks = bid >> 2, nip = (bid >> 1) & 1, wn = bid & 1;
    int lane = tid & 63, nilow = tid >> 6;
    int quad = lane >> 4, col = lane & 15;
    int h = wn * 64 + (nip * 2 + nilow) * 16 + col;
    int k0 = ks * 32 + quad * 8;
    float w[8];
#pragma unroll
    for (int t = 0; t < 8; ++t) w[t] = W1[(256 + k0 + t) * 128 + h] * 256.0f;
    uint2 u;
    u.x = pk4(w[0], w[1], w[2], w[3]);
    u.y = pk4(w[4], w[5], w[6], w[7]);
    reinterpret_cast<uint2*>(W1f8)[(bid * 64 + lane) * 2 + nilow] = u;
  } else {
    __shared__ float sN[128];
    int row = bid - 32;  // 0..1023
    int h = tid;
    sN[h] = node[row * 128 + h];
    __syncthreads();
    float ai = 0.f, aj = 0.f;
#pragma unroll 8
    for (int d = 0; d < 128; ++d) {
      float v = sN[d];
      ai = fmaf(v, W1[d * 128 + h], ai);
      aj = fmaf(v, W1[(128 + d) * 128 + h], aj);
    }
    PiB[row * 128 + h] = 256.0f * (ai + b1[h]);
    Pjf[row * 128 + h] = 256.0f * aj;
  }
}

// grid 2112 = b(4) * 528 unordered 8-group pairs (I<=J). 64 pairs/block, K=256 fp8.
// waves: wn2 = tid>>6 owns h-cols [wn2*32, wn2*32+32) (ni tiles 2wn2, 2wn2+1).
__global__ __launch_bounds__(256, 5) void main_k(
    const float* __restrict__ node, const float* __restrict__ baseL,
    const float* __restrict__ compL, const float* __restrict__ W1,
    const float* __restrict__ W2, const float* __restrict__ b2,
    const uint32_t* __restrict__ W1f8, const float* __restrict__ PiB,
    const float* __restrict__ Pjf, float* __restrict__ out) {
  // sF: [ks 0..7][mi 0..3][q 0..3][scol 0..15] 8B, scol=(col+2q+4(ks&3))&15 -> 16384 B
  //   (overlaid post-MFMA by sP: [64 pairs][40] fp32 partials, fwd@0..15, mir@20..35)
  // sPP: [16 rows][132] u32 {bf16 PiB' | bf16 Pjf'} (rows 0-7 I-group, 8-15 J-group)
  // sScal: [64 pairs] uint4 bf16x2 {bl',sig'}{cl',sig'} fwd then mirror
  __shared__ __align__(16) char smem[16384 + 8448 + 1024];
  char* sF = smem;
  uint32_t* sPP = reinterpret_cast<uint32_t*>(smem + 16384);
  uint4* sScal = reinterpret_cast<uint4*>(smem + 16384 + 8448);
  float* sP = reinterpret_cast<float*>(smem);  // overlay

  const int tid = threadIdx.x;
  const int bx = blockIdx.x;
  const int b = bx / 528;
  const int t = bx - b * 528;
  int tI = (int)((65.0f - sqrtf(4225.0f - 8.0f * (float)t)) * 0.5f);
  tI = (tI < 0) ? 0 : (tI > 31 ? 31 : tI);
  while (((65 * tI - tI * tI) >> 1) > t) --tI;
  while (tI < 31 && ((65 * (tI + 1) - (tI + 1) * (tI + 1)) >> 1) <= t) ++tI;
  const int tJ = tI + (t - ((65 * tI - tI * tI) >> 1));
  const int I0 = tI * 8, J0 = tJ * 8;
  const int rowB = b * 256;

  const int lane = tid & 63;
  const int wn2 = tid >> 6;
  const int col = lane & 15, quad = lane >> 4;

  // ---- B-fragments to registers (32 VGPR), L2-broadcast, held all kernel ----
  const int uB = ((wn2 & 1) << 1) | (wn2 >> 1);
  uint4 gB[8];
#pragma unroll
  for (int ks = 0; ks < 8; ++ks)
    gB[ks] = reinterpret_cast<const uint4*>(W1f8)[(ks * 4 + uB) * 64 + lane];

  // ---- stage sPP: 16 rows x 128 u32 {PiB'|Pjf'} bf16-packed, coalesced ----
#pragma unroll
  for (int it = 0; it < 2; ++it) {
    int fidx = it * 256 + tid;  // 512 float4 slots
    int row = fidx >> 5, d4 = fidx & 31;
    int gr = rowB + ((row < 8) ? (I0 + row) : (J0 + row - 8));
    float4 a = reinterpret_cast<const float4*>(PiB + (size_t)gr * 128)[d4];
    float4 c = reinterpret_cast<const float4*>(Pjf + (size_t)gr * 128)[d4];
    uint4 u;
    u.x = pkbf2(a.x, c.x);
    u.y = pkbf2(a.y, c.y);
    u.z = pkbf2(a.z, c.z);
    u.w = pkbf2(a.w, c.w);
    *reinterpret_cast<uint4*>(&sPP[row * 132 + d4 * 4]) = u;
  }

  // ---- stage scal (x256), fwd (tid<64) and mirror (tid in [64,128)) ----
  if (tid < 128) {
    int p = tid & 63, dir = tid >> 6;
    int iN = I0 + (p >> 3), jN = J0 + (p & 7);
    int rr = dir ? jN : iN, cc = dir ? iN : jN;
    float bl = fminf(fmaxf(baseL[(size_t)(rowB + rr) * 256 + cc], -20.f), 20.f);
    float cl = fminf(fmaxf(compL[(size_t)(rowB + rr) * 256 + cc], -20.f), 20.f);
    uint2 u;
    u.x = pkbf2(256.f * bl, 256.f / (1.f + __expf(-bl)));
    u.y = pkbf2(256.f * cl, 256.f / (1.f + __expf(-cl)));
    *reinterpret_cast<uint2*>(reinterpret_cast<char*>(&sScal[p]) + dir * 8) = u;
  }

  // ---- per-lane epilogue constants: W2 column + scal-MFMA B operands ----
  // B frag (16x16x32 bf16): lane holds B[k=quad*8+t][col]; only quad0 carries k=0..3:
  //   reg0 = {W1[512][h], W1[513][h]}, reg1 = {W1[514][h], W1[515][h]}, rest 0.
  float cW2[2];
  bf16x8 Bf[2];
#pragma unroll
  for (int ni = 0; ni < 2; ++ni) {
    int h = (wn2 * 2 + ni) * 16 + col;
    uint32_t w01 = pkbf2r(W1[512 * 128 + h], W1[513 * 128 + h]);
    uint32_t w23 = pkbf2r(W1[514 * 128 + h], W1[515 * 128 + h]);
    Bf[ni] = mkbf8(quad == 0 ? w01 : 0u, quad == 0 ? w23 : 0u, 0u, 0u);
    cW2[ni] = W2[h] * INV256;
  }
  const float b2v = b2[0];

  // ---- F-build: 64 pairs x 256 k fp8, node read direct from global (L1-hot) ----
  {
    const int d4 = tid & 31;  // float4 index in 128 dims
    const int rr = tid >> 5;  // j-row 0..7
    const int ks1 = d4 >> 3, qd = (d4 >> 1) & 3, kb = (d4 & 1) * 4;
    const int scolbase = 2 * qd + 4 * ks1;  // ks-rotation -> 2-way (free) write conflicts
    const float4 hj = *reinterpret_cast<const float4*>(node + (size_t)(rowB + J0 + rr) * 128 + d4 * 4);
#pragma unroll
    for (int ii = 0; ii < 8; ++ii) {
      const float4 hi = *reinterpret_cast<const float4*>(node + (size_t)(rowB + I0 + ii) * 128 + d4 * 4);
      uint32_t du = pk4(fabsf(hi.x - hj.x), fabsf(hi.y - hj.y),
                        fabsf(hi.z - hj.z), fabsf(hi.w - hj.w));
      uint32_t pu = pk4(hi.x * hj.x, hi.y * hj.y, hi.z * hj.z, hi.w * hj.w);
      int p = ii * 8 + rr;
      int colp = p & 15, mi = p >> 4;
      int scol = (colp + scolbase) & 15;
      uint32_t addr = mi * 512 + qd * 128 + scol * 8 + kb;
      *reinterpret_cast<uint32_t*>(sF + ks1 * 2048 + addr) = du;
      *reinterpret_cast<uint32_t*>(sF + (ks1 + 4) * 2048 + addr) = pu;
    }
  }
  __syncthreads();

  // ---- MFMA: acc[4 mi][2 ni], K=256; A from swizzled LDS, B from registers ----
  f32x4 acc[4][2] = {};
#pragma unroll
  for (int ks = 0; ks < 8; ++ks) {
    long bb0 = mk64(gB[ks].x, gB[ks].y);
    long bb1 = mk64(gB[ks].z, gB[ks].w);
    const int ascol = (col + 2 * quad + 4 * (ks & 3)) & 15;
    const char* aks = sF + ks * 2048 + quad * 128 + ascol * 8;
#pragma unroll
    for (int mi = 0; mi < 4; ++mi) {
      uint2 av = *reinterpret_cast<const uint2*>(aks + mi * 512);
      long aa = mk64(av.x, av.y);
      acc[mi][0] = __builtin_amdgcn_mfma_f32_16x16x32_fp8_fp8(aa, bb0, acc[mi][0], 0, 0, 0);
      acc[mi][1] = __builtin_amdgcn_mfma_f32_16x16x32_fp8_fp8(aa, bb1, acc[mi][1], 0, 0, 0);
    }
  }
  __syncthreads();  // sF reads done -> sP overlay writable

  // ---- epilogue: fwd+mirror, scal term via bf16 MFMA, shfl reduce (xor 1,2) ----
  uint32_t uJ[4][2];
#pragma unroll
  for (int r = 0; r < 4; ++r)
#pragma unroll
    for (int ni = 0; ni < 2; ++ni)
      uJ[r][ni] = sPP[(8 + (quad & 1) * 4 + r) * 132 + (wn2 * 2 + ni) * 16 + col];

  const f32x4 zf = {};
#pragma unroll
  for (int mi = 0; mi < 4; ++mi) {
    const int ii = mi * 2 + (quad >> 1);
    uint32_t uI[2];
#pragma unroll
    for (int ni = 0; ni < 2; ++ni)
      uI[ni] = sPP[ii * 132 + (wn2 * 2 + ni) * 16 + col];

    // scal-MFMA: A frag row = col (pair within tile), k=0..3 live on quad0 only.
    // sScal[mi*16+col] read by all lanes (same-addr broadcast across quads: free).
    uint4 sc4 = sScal[mi * 16 + col];
    bf16x8 af = mkbf8(quad == 0 ? sc4.x : 0u, quad == 0 ? sc4.y : 0u, 0u, 0u);
    bf16x8 am = mkbf8(quad == 0 ? sc4.z : 0u, quad == 0 ? sc4.w : 0u, 0u, 0u);
    f32x4 SF[2], SM[2];
#pragma unroll
    for (int ni = 0; ni < 2; ++ni) {
      SF[ni] = __builtin_amdgcn_mfma_f32_16x16x32_bf16(af, Bf[ni], zf, 0, 0, 0);
      SM[ni] = __builtin_amdgcn_mfma_f32_16x16x32_bf16(am, Bf[ni], zf, 0, 0, 0);
    }

#pragma unroll
    for (int r = 0; r < 4; ++r) {
      int p = mi * 16 + quad * 4 + r;  // C/D: pair row = quad*4 + r
      float vf = 0.f, vm = 0.f;
#pragma unroll
      for (int ni = 0; ni < 2; ++ni) {
        float piI = ulo(uI[ni]), pjI = uhi(uI[ni]);
        float piJ = ulo(uJ[r][ni]), pjJ = uhi(uJ[r][ni]);
        float a = acc[mi][ni][r];
        float pf = ((a + SF[ni][r]) + piI) + pjJ;
        float pm = ((a + SM[ni][r]) + piJ) + pjI;
        vf = fmaf(fmaxf(pf, 0.f), cW2[ni], vf);
        vm = fmaf(fmaxf(pm, 0.f), cW2[ni], vm);
      }
      vf += __shfl_xor(vf, 1);
      vf += __shfl_xor(vf, 2);
      vm += __shfl_xor(vm, 1);
      vm += __shfl_xor(vm, 2);
      if ((col & 3) == 0) {
        int part = wn2 * 4 + (col >> 2);
        sP[p * 40 + part] = vf;
        sP[p * 40 + 20 + part] = vm;
      }
    }
  }
  __syncthreads();

  // ---- final: sum 16 fwd + 16 mirror partials, symmetric store ----
  if (tid < 64) {
    int p = tid;
    const float4* pf4 = reinterpret_cast<const float4*>(sP + p * 40);
    const float4* pm4 = reinterpret_cast<const float4*>(sP + p * 40 + 20);
    float4 fa = pf4[0], fb = pf4[1], fc = pf4[2], fd = pf4[3];
    float4 ma = pm4[0], mb = pm4[1], mc = pm4[2], md = pm4[3];
    float sumF = (fa.x + fa.y + fa.z + fa.w) + (fb.x + fb.y + fb.z + fb.w) +
                 (fc.x + fc.y + fc.z + fc.w) + (fd.x + fd.y + fd.z + fd.w);
    float sumM = (ma.x + ma.y + ma.z + ma.w) + (mb.x + mb.y + mb.z + mb.w) +
                 (mc.x + mc.y + mc.z + mc.w) + (md.x + md.y + md.z + md.w);
    float val = 0.5f * (sumF + sumM) + b2v;
    int iN = I0 + (p >> 3), jN = J0 + (p & 7);
    if (iN == jN) val = -1e9f;
    out[(size_t)(rowB + iN) * 256 + jN] = val;
    out[(size_t)(rowB + jN) * 256 + iN] = val;
  }
}

extern "C" void kernel_launch(void* const* d_in, const int* in_sizes, int n_in,
                              void* d_out, int out_size, void* d_ws, size_t ws_size,
                              hipStream_t stream) {
  const float* node = (const float*)d_in[0];   // [4,256,128]
  const float* baseL = (const float*)d_in[1];  // [4,256,256]
  const float* compL = (const float*)d_in[2];  // [4,256,256]
  const float* W1 = (const float*)d_in[3];     // [516,128]
  const float* b1 = (const float*)d_in[4];     // [128]
  const float* W2 = (const float*)d_in[5];     // [128,1]
  const float* b2 = (const float*)d_in[6];     // [1]
  float* out = (float*)d_out;                  // [4,256,256] fp32

  char* ws = (char*)d_ws;
  float* PiB = (float*)(ws);                        // 512 KB
  float* Pjf = (float*)(ws + (512 << 10));          // 512 KB
  uint32_t* W1f8 = (uint32_t*)(ws + (1024 << 10));  // 32 KB

  pre_k<<<1056, 128, 0, stream>>>(node, W1, b1, PiB, Pjf, W1f8);
  main_k<<<2112, 256, 0, stream>>>(node, baseL, compL, W1, W2, b2, W1f8, PiB, Pjf, out);
}

// Round 3
// 89.766 us; speedup vs baseline: 1.0517x; 1.0351x over previous
//
#include <hip/hip_runtime.h>
#include <cstdint>

// B=4, N=256, D=128, HID=128, IN_DIM=516.
// G[i,j,h] = [|hi-hj| ; hi*hj] @ W1[256:512]  (K=256 fp8 MFMA, W x256) -- symmetric in (i,j)
// pre' = 256*pre = acc + PiB'[i,h] + Pjf'[j,h] + S(i,j,h)   (PiB',Pjf',scal' pre-scaled x256)
// S = scal'(p) @ W1[512:516]  (R9: K=4-padded-to-32 bf16 MFMA on the idle matrix pipe)
// L = relu(pre') @ (W2/256) + b2 ; out[i,j]=out[j,i]=0.5*(L_f+L_m); diag -1e9.
// R10 = R9 + pre_k MLP as bf16 MFMA GEMM (64 blocks, W1 read once: 134MB->8MB L2 traffic)
//       + PiB'/Pjf' emitted pre-packed {bf16|bf16} u32 (main_k staging = pure copy).

typedef float f32x4 __attribute__((ext_vector_type(4)));
typedef short bf16x8 __attribute__((ext_vector_type(8)));

#define INV256 0.00390625f

__device__ __forceinline__ uint32_t pk4(float a, float b, float c, float d) {
  uint32_t u = __builtin_amdgcn_cvt_pk_fp8_f32(a, b, 0, false);
  u = __builtin_amdgcn_cvt_pk_fp8_f32(c, d, u, true);
  return u;
}
__device__ __forceinline__ uint32_t pkbf2(float lo, float hi) {
  uint32_t l = __builtin_bit_cast(uint32_t, lo);
  uint32_t h = __builtin_bit_cast(uint32_t, hi);
  return (l >> 16) | (h & 0xffff0000u);
}
// round-to-nearest-even bf16 pack
__device__ __forceinline__ uint32_t rnebf(float x) {
  uint32_t u = __builtin_bit_cast(uint32_t, x);
  return (u + 0x7fffu + ((u >> 16) & 1u)) >> 16;
}
__device__ __forceinline__ uint32_t pkbf2r(float lo, float hi) {
  return rnebf(lo) | (rnebf(hi) << 16);
}
__device__ __forceinline__ float ulo(uint32_t u) {
  return __builtin_bit_cast(float, u << 16);
}
__device__ __forceinline__ float uhi(uint32_t u) {
  return __builtin_bit_cast(float, u & 0xffff0000u);
}
__device__ __forceinline__ long mk64(uint32_t lo, uint32_t hi) {
  return (long)((((unsigned long long)hi) << 32) | lo);
}
__device__ __forceinline__ bf16x8 mkbf8(uint32_t a, uint32_t b, uint32_t c, uint32_t d) {
  uint4 u;
  u.x = a; u.y = b; u.z = c; u.w = d;
  return __builtin_bit_cast(bf16x8, u);
}

// bid<32: pack fp8 B-image (lane-linear MFMA fragment order, values W1*256), 128 threads
// bid in [32,96): bf16 MFMA GEMM: rows 16/block, Ppk[row][h] = {bf16 PiB' | bf16 Pjf'}
//   PiB' = 256*(node@W1[0:128] + b1), Pjf' = 256*(node@W1[128:256]).
__global__ __launch_bounds__(256) void pre_k(const float* __restrict__ node,
                                             const float* __restrict__ W1,
                                             const float* __restrict__ b1,
                                             uint32_t* __restrict__ Ppk,
                                             uint32_t* __restrict__ W1f8) {
  int bid = blockIdx.x;
  int tid = threadIdx.x;
  if (bid < 32) {
    if (tid < 128) {
      int ks = bid >> 2, nip = (bid >> 1) & 1, wn = bid & 1;
      int lane = tid & 63, nilow = tid >> 6;
      int quad = lane >> 4, col = lane & 15;
      int h = wn * 64 + (nip * 2 + nilow) * 16 + col;
      int k0 = ks * 32 + quad * 8;
      float w[8];
#pragma unroll
      for (int t = 0; t < 8; ++t) w[t] = W1[(256 + k0 + t) * 128 + h] * 256.0f;
      uint2 u;
      u.x = pk4(w[0], w[1], w[2], w[3]);
      u.y = pk4(w[4], w[5], w[6], w[7]);
      reinterpret_cast<uint2*>(W1f8)[(bid * 64 + lane) * 2 + nilow] = u;
    }
    return;
  }
  // ---- GEMM part: block = 16 node rows, 4 waves x 64 h-cols, K=128 ----
  __shared__ float sC[16 * 264];  // +8 pad: rows offset 8 banks
  const int gb = bid - 32;        // 0..63
  const int gr0 = gb * 16;
  const int w = tid >> 6, lane = tid & 63, col = lane & 15, quad = lane >> 4;

  // A-frags: A[row=col][k=ks*32+quad*8+t] = node[gr0+col][k], RNE bf16
  bf16x8 Af[4];
  const float* arow = node + (size_t)(gr0 + col) * 128 + quad * 8;
#pragma unroll
  for (int ks = 0; ks < 4; ++ks) {
    float4 a0 = *reinterpret_cast<const float4*>(arow + ks * 32);
    float4 a1 = *reinterpret_cast<const float4*>(arow + ks * 32 + 4);
    Af[ks] = mkbf8(pkbf2r(a0.x, a0.y), pkbf2r(a0.z, a0.w),
                   pkbf2r(a1.x, a1.y), pkbf2r(a1.z, a1.w));
  }
  // waves 0,1 -> cols 0..127 (slab W1[0:128] -> PiB), waves 2,3 -> cols 128..255 (Pjf)
  const int colbase = w * 64;
  const float* wbase = W1 + (size_t)((w >> 1) * 128) * 128;
#pragma unroll
  for (int ni = 0; ni < 4; ++ni) {
    const int hh = (colbase + ni * 16 + col) & 127;
    f32x4 acc = {};
#pragma unroll
    for (int ks = 0; ks < 4; ++ks) {
      const float* wp = wbase + (size_t)(ks * 32 + quad * 8) * 128 + hh;
      bf16x8 Bf = mkbf8(pkbf2r(wp[0], wp[128]), pkbf2r(wp[256], wp[384]),
                        pkbf2r(wp[512], wp[640]), pkbf2r(wp[768], wp[896]));
      acc = __builtin_amdgcn_mfma_f32_16x16x32_bf16(Af[ks], Bf, acc, 0, 0, 0);
    }
#pragma unroll
    for (int r = 0; r < 4; ++r)
      sC[(quad * 4 + r) * 264 + colbase + ni * 16 + col] = acc[r];
  }
  __syncthreads();
  // pack: thread (row=tid>>4, hq=tid&15) -> 8 h, Ppk = {bf16 PiB' | bf16 Pjf'}
  {
    const int row = tid >> 4, hq = tid & 15;
    uint32_t ov[8];
#pragma unroll
    for (int hh = 0; hh < 8; ++hh) {
      int h = hq * 8 + hh;
      float pib = 256.f * (sC[row * 264 + h] + b1[h]);
      float pjf = 256.f * sC[row * 264 + 128 + h];
      ov[hh] = pkbf2r(pib, pjf);
    }
    uint4* dst = reinterpret_cast<uint4*>(Ppk + (size_t)(gr0 + row) * 128 + hq * 8);
    dst[0] = *reinterpret_cast<uint4*>(&ov[0]);
    dst[1] = *reinterpret_cast<uint4*>(&ov[4]);
  }
}

// grid 2112 = b(4) * 528 unordered 8-group pairs (I<=J). 64 pairs/block, K=256 fp8.
// waves: wn2 = tid>>6 owns h-cols [wn2*32, wn2*32+32) (ni tiles 2wn2, 2wn2+1).
__global__ __launch_bounds__(256, 5) void main_k(
    const float* __restrict__ node, const float* __restrict__ baseL,
    const float* __restrict__ compL, const float* __restrict__ W1,
    const float* __restrict__ W2, const float* __restrict__ b2,
    const uint32_t* __restrict__ W1f8, const uint32_t* __restrict__ Ppk,
    float* __restrict__ out) {
  // sF: [ks 0..7][mi 0..3][q 0..3][scol 0..15] 8B, scol=(col+2q+4(ks&3))&15 -> 16384 B
  //   (overlaid post-MFMA by sP: [64 pairs][40] fp32 partials, fwd@0..15, mir@20..35)
  // sPP: [16 rows][132] u32 {bf16 PiB' | bf16 Pjf'} (rows 0-7 I-group, 8-15 J-group)
  // sScal: [64 pairs] uint4 bf16x2 {bl',sig'}{cl',sig'} fwd then mirror
  __shared__ __align__(16) char smem[16384 + 8448 + 1024];
  char* sF = smem;
  uint32_t* sPP = reinterpret_cast<uint32_t*>(smem + 16384);
  uint4* sScal = reinterpret_cast<uint4*>(smem + 16384 + 8448);
  float* sP = reinterpret_cast<float*>(smem);  // overlay

  const int tid = threadIdx.x;
  const int bx = blockIdx.x;
  const int b = bx / 528;
  const int t = bx - b * 528;
  int tI = (int)((65.0f - sqrtf(4225.0f - 8.0f * (float)t)) * 0.5f);
  tI = (tI < 0) ? 0 : (tI > 31 ? 31 : tI);
  while (((65 * tI - tI * tI) >> 1) > t) --tI;
  while (tI < 31 && ((65 * (tI + 1) - (tI + 1) * (tI + 1)) >> 1) <= t) ++tI;
  const int tJ = tI + (t - ((65 * tI - tI * tI) >> 1));
  const int I0 = tI * 8, J0 = tJ * 8;
  const int rowB = b * 256;

  const int lane = tid & 63;
  const int wn2 = tid >> 6;
  const int col = lane & 15, quad = lane >> 4;

  // ---- B-fragments to registers (32 VGPR), L2-broadcast, held all kernel ----
  const int uB = ((wn2 & 1) << 1) | (wn2 >> 1);
  uint4 gB[8];
#pragma unroll
  for (int ks = 0; ks < 8; ++ks)
    gB[ks] = reinterpret_cast<const uint4*>(W1f8)[(ks * 4 + uB) * 64 + lane];

  // ---- stage sPP: pure copy of pre-packed Ppk rows (16 x 128 u32) ----
#pragma unroll
  for (int it = 0; it < 2; ++it) {
    int fidx = it * 256 + tid;  // 512 uint4 slots
    int row = fidx >> 5, q = fidx & 31;
    int gr = rowB + ((row < 8) ? (I0 + row) : (J0 + row - 8));
    uint4 u = reinterpret_cast<const uint4*>(Ppk + (size_t)gr * 128)[q];
    *reinterpret_cast<uint4*>(&sPP[row * 132 + q * 4]) = u;
  }

  // ---- stage scal (x256), fwd (tid<64) and mirror (tid in [64,128)) ----
  if (tid < 128) {
    int p = tid & 63, dir = tid >> 6;
    int iN = I0 + (p >> 3), jN = J0 + (p & 7);
    int rr = dir ? jN : iN, cc = dir ? iN : jN;
    float bl = fminf(fmaxf(baseL[(size_t)(rowB + rr) * 256 + cc], -20.f), 20.f);
    float cl = fminf(fmaxf(compL[(size_t)(rowB + rr) * 256 + cc], -20.f), 20.f);
    uint2 u;
    u.x = pkbf2(256.f * bl, 256.f / (1.f + __expf(-bl)));
    u.y = pkbf2(256.f * cl, 256.f / (1.f + __expf(-cl)));
    *reinterpret_cast<uint2*>(reinterpret_cast<char*>(&sScal[p]) + dir * 8) = u;
  }

  // ---- per-lane epilogue constants: W2 column + scal-MFMA B operands ----
  // B frag (16x16x32 bf16): lane holds B[k=quad*8+t][col]; only quad0 carries k=0..3:
  //   reg0 = {W1[512][h], W1[513][h]}, reg1 = {W1[514][h], W1[515][h]}, rest 0.
  float cW2[2];
  bf16x8 Bf[2];
#pragma unroll
  for (int ni = 0; ni < 2; ++ni) {
    int h = (wn2 * 2 + ni) * 16 + col;
    uint32_t w01 = pkbf2r(W1[512 * 128 + h], W1[513 * 128 + h]);
    uint32_t w23 = pkbf2r(W1[514 * 128 + h], W1[515 * 128 + h]);
    Bf[ni] = mkbf8(quad == 0 ? w01 : 0u, quad == 0 ? w23 : 0u, 0u, 0u);
    cW2[ni] = W2[h] * INV256;
  }
  const float b2v = b2[0];

  // ---- F-build: 64 pairs x 256 k fp8, node read direct from global (L1-hot) ----
  {
    const int d4 = tid & 31;  // float4 index in 128 dims
    const int rr = tid >> 5;  // j-row 0..7
    const int ks1 = d4 >> 3, qd = (d4 >> 1) & 3, kb = (d4 & 1) * 4;
    const int scolbase = 2 * qd + 4 * ks1;  // ks-rotation -> 2-way (free) write conflicts
    const float4 hj = *reinterpret_cast<const float4*>(node + (size_t)(rowB + J0 + rr) * 128 + d4 * 4);
#pragma unroll
    for (int ii = 0; ii < 8; ++ii) {
      const float4 hi = *reinterpret_cast<const float4*>(node + (size_t)(rowB + I0 + ii) * 128 + d4 * 4);
      uint32_t du = pk4(fabsf(hi.x - hj.x), fabsf(hi.y - hj.y),
                        fabsf(hi.z - hj.z), fabsf(hi.w - hj.w));
      uint32_t pu = pk4(hi.x * hj.x, hi.y * hj.y, hi.z * hj.z, hi.w * hj.w);
      int p = ii * 8 + rr;
      int colp = p & 15, mi = p >> 4;
      int scol = (colp + scolbase) & 15;
      uint32_t addr = mi * 512 + qd * 128 + scol * 8 + kb;
      *reinterpret_cast<uint32_t*>(sF + ks1 * 2048 + addr) = du;
      *reinterpret_cast<uint32_t*>(sF + (ks1 + 4) * 2048 + addr) = pu;
    }
  }
  __syncthreads();

  // ---- MFMA: acc[4 mi][2 ni], K=256; A from swizzled LDS, B from registers ----
  f32x4 acc[4][2] = {};
#pragma unroll
  for (int ks = 0; ks < 8; ++ks) {
    long bb0 = mk64(gB[ks].x, gB[ks].y);
    long bb1 = mk64(gB[ks].z, gB[ks].w);
    const int ascol = (col + 2 * quad + 4 * (ks & 3)) & 15;
    const char* aks = sF + ks * 2048 + quad * 128 + ascol * 8;
#pragma unroll
    for (int mi = 0; mi < 4; ++mi) {
      uint2 av = *reinterpret_cast<const uint2*>(aks + mi * 512);
      long aa = mk64(av.x, av.y);
      acc[mi][0] = __builtin_amdgcn_mfma_f32_16x16x32_fp8_fp8(aa, bb0, acc[mi][0], 0, 0, 0);
      acc[mi][1] = __builtin_amdgcn_mfma_f32_16x16x32_fp8_fp8(aa, bb1, acc[mi][1], 0, 0, 0);
    }
  }
  __syncthreads();  // sF reads done -> sP overlay writable

  // ---- epilogue: fwd+mirror, scal term via bf16 MFMA, shfl reduce (xor 1,2) ----
  uint32_t uJ[4][2];
#pragma unroll
  for (int r = 0; r < 4; ++r)
#pragma unroll
    for (int ni = 0; ni < 2; ++ni)
      uJ[r][ni] = sPP[(8 + (quad & 1) * 4 + r) * 132 + (wn2 * 2 + ni) * 16 + col];

  const f32x4 zf = {};
#pragma unroll
  for (int mi = 0; mi < 4; ++mi) {
    const int ii = mi * 2 + (quad >> 1);
    uint32_t uI[2];
#pragma unroll
    for (int ni = 0; ni < 2; ++ni)
      uI[ni] = sPP[ii * 132 + (wn2 * 2 + ni) * 16 + col];

    // scal-MFMA: A frag row = col (pair within tile), k=0..3 live on quad0 only.
    uint4 sc4 = sScal[mi * 16 + col];
    bf16x8 af = mkbf8(quad == 0 ? sc4.x : 0u, quad == 0 ? sc4.y : 0u, 0u, 0u);
    bf16x8 am = mkbf8(quad == 0 ? sc4.z : 0u, quad == 0 ? sc4.w : 0u, 0u, 0u);
    f32x4 SF[2], SM[2];
#pragma unroll
    for (int ni = 0; ni < 2; ++ni) {
      SF[ni] = __builtin_amdgcn_mfma_f32_16x16x32_bf16(af, Bf[ni], zf, 0, 0, 0);
      SM[ni] = __builtin_amdgcn_mfma_f32_16x16x32_bf16(am, Bf[ni], zf, 0, 0, 0);
    }

#pragma unroll
    for (int r = 0; r < 4; ++r) {
      int p = mi * 16 + quad * 4 + r;  // C/D: pair row = quad*4 + r
      float vf = 0.f, vm = 0.f;
#pragma unroll
      for (int ni = 0; ni < 2; ++ni) {
        float piI = ulo(uI[ni]), pjI = uhi(uI[ni]);
        float piJ = ulo(uJ[r][ni]), pjJ = uhi(uJ[r][ni]);
        float a = acc[mi][ni][r];
        float pf = ((a + SF[ni][r]) + piI) + pjJ;
        float pm = ((a + SM[ni][r]) + piJ) + pjI;
        vf = fmaf(fmaxf(pf, 0.f), cW2[ni], vf);
        vm = fmaf(fmaxf(pm, 0.f), cW2[ni], vm);
      }
      vf += __shfl_xor(vf, 1);
      vf += __shfl_xor(vf, 2);
      vm += __shfl_xor(vm, 1);
      vm += __shfl_xor(vm, 2);
      if ((col & 3) == 0) {
        int part = wn2 * 4 + (col >> 2);
        sP[p * 40 + part] = vf;
        sP[p * 40 + 20 + part] = vm;
      }
    }
  }
  __syncthreads();

  // ---- final: sum 16 fwd + 16 mirror partials, symmetric store ----
  if (tid < 64) {
    int p = tid;
    const float4* pf4 = reinterpret_cast<const float4*>(sP + p * 40);
    const float4* pm4 = reinterpret_cast<const float4*>(sP + p * 40 + 20);
    float4 fa = pf4[0], fb = pf4[1], fc = pf4[2], fd = pf4[3];
    float4 ma = pm4[0], mb = pm4[1], mc = pm4[2], md = pm4[3];
    float sumF = (fa.x + fa.y + fa.z + fa.w) + (fb.x + fb.y + fb.z + fb.w) +
                 (fc.x + fc.y + fc.z + fc.w) + (fd.x + fd.y + fd.z + fd.w);
    float sumM = (ma.x + ma.y + ma.z + ma.w) + (mb.x + mb.y + mb.z + mb.w) +
                 (mc.x + mc.y + mc.z + mc.w) + (md.x + md.y + md.z + md.w);
    float val = 0.5f * (sumF + sumM) + b2v;
    int iN = I0 + (p >> 3), jN = J0 + (p & 7);
    if (iN == jN) val = -1e9f;
    out[(size_t)(rowB + iN) * 256 + jN] = val;
    out[(size_t)(rowB + jN) * 256 + iN] = val;
  }
}

extern "C" void kernel_launch(void* const* d_in, const int* in_sizes, int n_in,
                              void* d_out, int out_size, void* d_ws, size_t ws_size,
                              hipStream_t stream) {
  const float* node = (const float*)d_in[0];   // [4,256,128]
  const float* baseL = (const float*)d_in[1];  // [4,256,256]
  const float* compL = (const float*)d_in[2];  // [4,256,256]
  const float* W1 = (const float*)d_in[3];     // [516,128]
  const float* b1 = (const float*)d_in[4];     // [128]
  const float* W2 = (const float*)d_in[5];     // [128,1]
  const float* b2 = (const float*)d_in[6];     // [1]
  float* out = (float*)d_out;                  // [4,256,256] fp32

  char* ws = (char*)d_ws;
  uint32_t* Ppk = (uint32_t*)ws;                   // 512 KB packed {PiB'|Pjf'}
  uint32_t* W1f8 = (uint32_t*)(ws + (512 << 10));  // 32 KB

  pre_k<<<96, 256, 0, stream>>>(node, W1, b1, Ppk, W1f8);
  main_k<<<2112, 256, 0, stream>>>(node, baseL, compL, W1, W2, b2, W1f8, Ppk, out);
}